// Round 6
// baseline (1840.768 us; speedup 1.0000x reference)
//
#include <hip/hip_runtime.h>
#include <hip/hip_bf16.h>
#include <stdint.h>

typedef __attribute__((ext_vector_type(8))) short short8;
typedef __attribute__((ext_vector_type(4))) float f32x4;

#define AS1 __attribute__((address_space(1)))
#define AS3 __attribute__((address_space(3)))

__device__ __forceinline__ short f2bf(float x) {
    __hip_bfloat16 h = __float2bfloat16(x);
    union { __hip_bfloat16 h; short s; } u; u.h = h; return u.s;
}

__device__ __forceinline__ void gload_lds16(const short* g, short* l) {
    __builtin_amdgcn_global_load_lds((const AS1 void*)g, (AS3 void*)l, 16, 0, 0);
}

#define BAR()        asm volatile("s_barrier" ::: "memory")
#define VMCNT_BAR(N) asm volatile("s_waitcnt vmcnt(" #N ")\n\ts_barrier" ::: "memory")
#define LGKM0_BAR()  asm volatile("s_waitcnt lgkmcnt(0)\n\ts_barrier" ::: "memory")

// ---------------------------------------------------------------------------
// 256x256 tile, BK=64, 512 threads = 8 waves (2M x 4N).
// LDS [2buf][2kh][256][32] x {A,B} = 128 KiB; T2 chunk-XOR swizzle
// (conflict-free, measured 0). NEW (r6): register-double-buffered frag
// pipeline -- each phase issues the NEXT phase's ds_reads (afN/bN sets) and
// runs 16 MFMA on the previous phase's regs, so the LDS port (578 cy/phase)
// overlaps the MFMA pipe (621 cy/phase) instead of serializing (r5 model
// matched measurement at 578+621 per phase). Cross-tile reads sit after
// ph3's VMCNT_BAR(4) (exactly drains next-tile kh0). Tile-end sync =
// lgkmcnt(0)+barrier (protects buf being re-staged against pipelined reads).
// Syncs/K-tile: 8 -> 5. TAPS==3: conv path (padded [2][8194][4096] rows).
// ---------------------------------------------------------------------------
template<int TAPS, bool F32OUT>
__global__ __launch_bounds__(512, 2) void gemm256(
    const short* __restrict__ A, int lda,
    const short* __restrict__ BT, int ldb, long long tapB,
    void* __restrict__ Cout, int ldc,
    const float* __restrict__ bias, int Ktiles)
{
    __shared__ __align__(16) short As[2 * 2 * 256 * 32];
    __shared__ __align__(16) short Bs[2 * 2 * 256 * 32];
    const int tid = threadIdx.x, lane = tid & 63, wid = tid >> 6;
    const int wm = wid >> 2, wn = wid & 3;
    const int m0 = blockIdx.y * 256, n0 = blockIdx.x * 256;
    const size_t arow0 = (TAPS == 3) ? ((size_t)(m0 >> 13) * 8194 + (size_t)(m0 & 8191))
                                     : (size_t)m0;
    const size_t ldaS = (size_t)lda, ldbS = (size_t)ldb, tapBS = (size_t)tapB;
    const short* Abase0 = A + arow0 * ldaS;
    const short* Bbase0 = BT + (size_t)n0 * ldbS;
    const int c15 = lane & 15, g4 = (lane >> 4) * 4;
    const int swz = ((lane >> 4) ^ ((c15 >> 1) & 3)) * 8;
    const int srow = tid >> 2;
    const int schunk = (((tid & 3) ^ ((tid >> 3) & 3)) * 8);

#define STG_A(u, kh, buf) do { \
    const int tp_ = (TAPS == 3) ? ((u) >> 6) : 0; \
    const int kc_ = (TAPS == 3) ? (((u) & 63) << 6) : ((u) << 6); \
    const short* g_ = Abase0 + (size_t)tp_ * ldaS + kc_ + (kh) * 32 \
                      + (size_t)srow * ldaS + schunk; \
    short* l_ = As + (buf) * 16384 + (kh) * 8192 + wid * 512; \
    gload_lds16(g_, l_); \
    gload_lds16(g_ + 128 * ldaS, l_ + 4096); \
} while (0)

#define STG_B(u, kh, buf) do { \
    const int tp_ = (TAPS == 3) ? ((u) >> 6) : 0; \
    const int kc_ = (TAPS == 3) ? (((u) & 63) << 6) : ((u) << 6); \
    const short* g_ = Bbase0 + (size_t)tp_ * tapBS + kc_ + (kh) * 32 \
                      + (size_t)srow * ldbS + schunk; \
    short* l_ = Bs + (buf) * 16384 + (kh) * 8192 + wid * 512; \
    gload_lds16(g_, l_); \
    gload_lds16(g_ + 128 * ldbS, l_ + 4096); \
} while (0)

#define LDA_(buf, kk, mi) (*(const short8*)(As + (buf) * 16384 + (kk) * 8192 \
                           + (wm * 128 + (mi) * 16 + c15) * 32 + swz))
#define LDB_(buf, kk, nj) (*(const short8*)(Bs + (buf) * 16384 + (kk) * 8192 \
                           + (wn * 64 + (nj) * 16 + c15) * 32 + swz))

#define MM(mi, nj, Av, Bv) acc[mi][nj] = \
    __builtin_amdgcn_mfma_f32_16x16x32_bf16(Av, Bv, acc[mi][nj], 0, 0, 0)

#define MFMA16(MB, A0, A1, A2, A3, B0, B1, B2, B3) do { \
    __builtin_amdgcn_s_setprio(1); \
    MM((MB)+0, 0, A0, B0); MM((MB)+0, 1, A0, B1); MM((MB)+0, 2, A0, B2); MM((MB)+0, 3, A0, B3); \
    MM((MB)+1, 0, A1, B0); MM((MB)+1, 1, A1, B1); MM((MB)+1, 2, A1, B2); MM((MB)+1, 3, A1, B3); \
    MM((MB)+2, 0, A2, B0); MM((MB)+2, 1, A2, B1); MM((MB)+2, 2, A2, B2); MM((MB)+2, 3, A2, B3); \
    MM((MB)+3, 0, A3, B0); MM((MB)+3, 1, A3, B1); MM((MB)+3, 2, A3, B2); MM((MB)+3, 3, A3, B3); \
    __builtin_amdgcn_s_setprio(0); \
} while (0)

    f32x4 acc[8][4];
    #pragma unroll
    for (int i = 0; i < 8; ++i)
        #pragma unroll
        for (int j = 0; j < 4; ++j)
            acc[i][j] = (f32x4){0.f, 0.f, 0.f, 0.f};

    short8 afC0, afC1, afC2, afC3;   // "current" A frags
    short8 afN0, afN1, afN2, afN3;   // "next" A frags
    short8 bC0, bC1, bC2, bC3;       // B frags for kk pair in flight
    short8 bN0, bN1, bN2, bN3;

    // prologue: stage tile 0 (Akh0,Bkh0,Akh1,Bkh1), then load ph0 frags
    STG_A(0, 0, 0); STG_B(0, 0, 0); STG_A(0, 1, 0); STG_B(0, 1, 0);
    VMCNT_BAR(4);   // kh0 of tile 0 resident; kh1 still in flight
    afC0 = LDA_(0, 0, 0); afC1 = LDA_(0, 0, 1); afC2 = LDA_(0, 0, 2); afC3 = LDA_(0, 0, 3);
    bC0 = LDB_(0, 0, 0); bC1 = LDB_(0, 0, 1); bC2 = LDB_(0, 0, 2); bC3 = LDB_(0, 0, 3);

    for (int t = 0; t < Ktiles; ++t) {
        const int c = t & 1, nb = c ^ 1;
        const bool st = (t + 1 < Ktiles);
        const int u = t + 1;

        // ---- ph0: compute kk0 x mi0-3; load kk0 x mi4-7 ----
        if (st) STG_A(u, 0, nb);
        BAR();
        afN0 = LDA_(c, 0, 4); afN1 = LDA_(c, 0, 5); afN2 = LDA_(c, 0, 6); afN3 = LDA_(c, 0, 7);
        MFMA16(0, afC0, afC1, afC2, afC3, bC0, bC1, bC2, bC3);

        // ---- ph1: compute kk0 x mi4-7; load kk1 x mi0-3 + kk1 B ----
        if (st) STG_B(u, 0, nb);
        if (st) { VMCNT_BAR(4); } else { VMCNT_BAR(0); }   // kh1(t) resident
        afC0 = LDA_(c, 1, 0); afC1 = LDA_(c, 1, 1); afC2 = LDA_(c, 1, 2); afC3 = LDA_(c, 1, 3);
        bN0 = LDB_(c, 1, 0); bN1 = LDB_(c, 1, 1); bN2 = LDB_(c, 1, 2); bN3 = LDB_(c, 1, 3);
        MFMA16(4, afN0, afN1, afN2, afN3, bC0, bC1, bC2, bC3);

        // ---- ph2: compute kk1 x mi0-3; load kk1 x mi4-7 ----
        if (st) STG_A(u, 1, nb);
        BAR();
        afN0 = LDA_(c, 1, 4); afN1 = LDA_(c, 1, 5); afN2 = LDA_(c, 1, 6); afN3 = LDA_(c, 1, 7);
        MFMA16(0, afC0, afC1, afC2, afC3, bN0, bN1, bN2, bN3);

        // ---- ph3: compute kk1 x mi4-7; load next tile's kk0 frags ----
        if (st) STG_B(u, 1, nb);
        if (st) { VMCNT_BAR(4); } else { VMCNT_BAR(0); }   // kh0(t+1) resident
        if (st) {
            afC0 = LDA_(nb, 0, 0); afC1 = LDA_(nb, 0, 1);
            afC2 = LDA_(nb, 0, 2); afC3 = LDA_(nb, 0, 3);
            bC0 = LDB_(nb, 0, 0); bC1 = LDB_(nb, 0, 1);
            bC2 = LDB_(nb, 0, 2); bC3 = LDB_(nb, 0, 3);
        }
        MFMA16(4, afN0, afN1, afN2, afN3, bN0, bN1, bN2, bN3);
        LGKM0_BAR();   // drain pipelined reads before next tile re-stages buf c
    }

    float bv[4];
    #pragma unroll
    for (int nj = 0; nj < 4; ++nj)
        bv[nj] = bias ? bias[n0 + wn * 64 + nj * 16 + c15] : 0.f;
    #pragma unroll
    for (int mi = 0; mi < 8; ++mi) {
        #pragma unroll
        for (int r = 0; r < 4; ++r) {
            const size_t row = (size_t)m0 + wm * 128 + mi * 16 + g4 + r;
            #pragma unroll
            for (int nj = 0; nj < 4; ++nj) {
                const int col = n0 + wn * 64 + nj * 16 + c15;
                const float v = acc[mi][nj][r] + bv[nj];
                if (F32OUT) ((float*)Cout)[row * (size_t)ldc + col] = v;
                else        ((short*)Cout)[row * (size_t)ldc + col] = f2bf(v);
            }
        }
    }
#undef STG_A
#undef STG_B
#undef LDA_
#undef LDB_
#undef MM
#undef MFMA16
}

// ---------------------------------------------------------------------------
// Per (head, block) causal attention on 128x128 tiles. qh/kh/vh: [16384][1024]
// bf16 (col = h*64+e). 4 waves x 32 q-rows.
// ---------------------------------------------------------------------------
__global__ __launch_bounds__(256) void attn_kernel(
    const short* __restrict__ qh, const short* __restrict__ kh,
    const short* __restrict__ vh, short* __restrict__ obuf)
{
    __shared__ __align__(16) char smem[54272];
    short* qs = (short*)smem;                 // [128][72]
    short* ks = (short*)smem + 9216;          // [128][72]
    short* vt = (short*)(smem + 36864);       // [64][136]  (vh transposed)
    short* ps = (short*)smem;                 // [128][136] (reuses qs+ks region)
    short* os = (short*)smem;                 // [128][72]  (reused post-PV)

    const int tid = threadIdx.x, lane = tid & 63, wid = tid >> 6;
    const int h = blockIdx.x, b = blockIdx.y;
    const size_t base = (size_t)b * 128 * 1024 + (size_t)h * 64;

    for (int i = tid; i < 1024; i += 256) {
        const int row = i >> 3, c8 = i & 7;
        const size_t g = base + (size_t)row * 1024 + c8 * 8;
        *(short8*)(qs + row * 72 + c8 * 8) = *(const short8*)(qh + g);
        *(short8*)(ks + row * 72 + c8 * 8) = *(const short8*)(kh + g);
        short8 vv = *(const short8*)(vh + g);
        #pragma unroll
        for (int j = 0; j < 8; ++j) vt[(c8 * 8 + j) * 136 + row] = vv[j];
    }
    __syncthreads();

    const int c15 = lane & 15, g8 = (lane >> 4) * 8, g4 = (lane >> 4) * 4;
    const int r0 = wid * 32;

    f32x4 sacc[2][8];
    #pragma unroll
    for (int mi = 0; mi < 2; ++mi)
        #pragma unroll
        for (int nj = 0; nj < 8; ++nj)
            sacc[mi][nj] = (f32x4){0.f, 0.f, 0.f, 0.f};
    #pragma unroll
    for (int kk = 0; kk < 2; ++kk) {
        short8 aq[2];
        #pragma unroll
        for (int mi = 0; mi < 2; ++mi)
            aq[mi] = *(const short8*)(qs + (r0 + mi * 16 + c15) * 72 + kk * 32 + g8);
        #pragma unroll
        for (int nj = 0; nj < 8; ++nj) {
            short8 bk8 = *(const short8*)(ks + (nj * 16 + c15) * 72 + kk * 32 + g8);
            #pragma unroll
            for (int mi = 0; mi < 2; ++mi)
                sacc[mi][nj] = __builtin_amdgcn_mfma_f32_16x16x32_bf16(
                    aq[mi], bk8, sacc[mi][nj], 0, 0, 0);
        }
    }
    __syncthreads();

    #pragma unroll
    for (int mi = 0; mi < 2; ++mi) {
        #pragma unroll
        for (int r = 0; r < 4; ++r) {
            const int qrow = r0 + mi * 16 + g4 + r;
            float m = -3.0e38f, pv[8];
            #pragma unroll
            for (int nj = 0; nj < 8; ++nj) {
                float s = sacc[mi][nj][r] * 0.125f;
                if (nj * 16 + c15 > qrow) s = -1.0e9f;
                pv[nj] = s; m = fmaxf(m, s);
            }
            #pragma unroll
            for (int off = 8; off >= 1; off >>= 1) m = fmaxf(m, __shfl_xor(m, off));
            float sum = 0.f;
            #pragma unroll
            for (int nj = 0; nj < 8; ++nj) { float p = __expf(pv[nj] - m); pv[nj] = p; sum += p; }
            #pragma unroll
            for (int off = 8; off >= 1; off >>= 1) sum += __shfl_xor(sum, off);
            const float inv = 1.0f / sum;
            #pragma unroll
            for (int nj = 0; nj < 8; ++nj)
                ps[qrow * 136 + nj * 16 + c15] = f2bf(pv[nj] * inv);
        }
    }
    __syncthreads();

    f32x4 oacc[2][4];
    #pragma unroll
    for (int mi = 0; mi < 2; ++mi)
        #pragma unroll
        for (int nj = 0; nj < 4; ++nj)
            oacc[mi][nj] = (f32x4){0.f, 0.f, 0.f, 0.f};
    #pragma unroll
    for (int kt = 0; kt < 4; ++kt) {
        short8 ap[2];
        #pragma unroll
        for (int mi = 0; mi < 2; ++mi)
            ap[mi] = *(const short8*)(ps + (r0 + mi * 16 + c15) * 136 + kt * 32 + g8);
        #pragma unroll
        for (int nj = 0; nj < 4; ++nj) {
            short8 bv8 = *(const short8*)(vt + (nj * 16 + c15) * 136 + kt * 32 + g8);
            #pragma unroll
            for (int mi = 0; mi < 2; ++mi)
                oacc[mi][nj] = __builtin_amdgcn_mfma_f32_16x16x32_bf16(
                    ap[mi], bv8, oacc[mi][nj], 0, 0, 0);
        }
    }
    __syncthreads();

    #pragma unroll
    for (int mi = 0; mi < 2; ++mi)
        #pragma unroll
        for (int r = 0; r < 4; ++r)
            #pragma unroll
            for (int nj = 0; nj < 4; ++nj)
                os[(r0 + mi * 16 + g4 + r) * 72 + nj * 16 + c15] = f2bf(oacc[mi][nj][r]);
    __syncthreads();

    for (int i = tid; i < 1024; i += 256) {
        const int row = i >> 3, c8 = i & 7;
        *(short8*)(obuf + base + (size_t)row * 1024 + c8 * 8) =
            *(const short8*)(os + row * 72 + c8 * 8);
    }
}

// ---------------------------------------------------------------------------
__global__ void pad_convert_inputs(const float* __restrict__ in, short* __restrict__ out)
{
    const int row = blockIdx.x;                 // [0, 16388)
    const int n = row / 8194, l = row % 8194;
    short* orow = out + (size_t)row * 4096;
    if (l == 0 || l == 8193) {
        for (int i = threadIdx.x; i < 512; i += 256) {
            uint4 z; z.x = z.y = z.z = z.w = 0u;
            *(uint4*)(orow + i * 8) = z;
        }
    } else {
        const float* irow = in + ((size_t)n * 8192 + (l - 1)) * 4096;
        for (int i = threadIdx.x; i < 512; i += 256) {
            float4 a = *(const float4*)(irow + i * 8);
            float4 b = *(const float4*)(irow + i * 8 + 4);
            short8 v;
            v[0] = f2bf(a.x); v[1] = f2bf(a.y); v[2] = f2bf(a.z); v[3] = f2bf(a.w);
            v[4] = f2bf(b.x); v[5] = f2bf(b.y); v[6] = f2bf(b.z); v[7] = f2bf(b.w);
            *(short8*)(orow + i * 8) = v;
        }
    }
}

__global__ void transpose_convert(const float* __restrict__ in, short* __restrict__ out,
                                  int R, int C)
{
    __shared__ float tile[32][33];
    const int tx = threadIdx.x & 31, ty = threadIdx.x >> 5;   // 32 x 8
    const int bx = blockIdx.x * 32, by = blockIdx.y * 32;
    #pragma unroll
    for (int i = 0; i < 32; i += 8)
        tile[ty + i][tx] = in[(size_t)(by + ty + i) * C + bx + tx];
    __syncthreads();
    #pragma unroll
    for (int i = 0; i < 32; i += 8)
        out[(size_t)(bx + ty + i) * R + by + tx] = f2bf(tile[tx][ty + i]);
}

__global__ void convert_bf16(const float* __restrict__ in, short* __restrict__ out, int n8)
{
    const int idx = blockIdx.x * 256 + threadIdx.x;
    if (idx < n8) {
        float4 a = *(const float4*)(in + (size_t)idx * 8);
        float4 b = *(const float4*)(in + (size_t)idx * 8 + 4);
        short8 v;
        v[0] = f2bf(a.x); v[1] = f2bf(a.y); v[2] = f2bf(a.z); v[3] = f2bf(a.w);
        v[4] = f2bf(b.x); v[5] = f2bf(b.y); v[6] = f2bf(b.z); v[7] = f2bf(b.w);
        *(short8*)(out + (size_t)idx * 8) = v;
    }
}

__global__ void fuse_bias(const float* __restrict__ bo, const float* __restrict__ projw,
                          const float* __restrict__ projb, float* __restrict__ outb)
{
    const int j = blockIdx.x * 256 + threadIdx.x;   // 4096
    float s = projb[j];
    for (int w = 0; w < 1024; ++w) s = fmaf(bo[w], projw[(size_t)w * 4096 + j], s);
    outb[j] = s;
}

// ---------------------------------------------------------------------------
extern "C" void kernel_launch(void* const* d_in, const int* in_sizes, int n_in,
                              void* d_out, int out_size, void* d_ws, size_t ws_size,
                              hipStream_t stream)
{
    const float* inputs = (const float*)d_in[0];
    const float* conv_w = (const float*)d_in[1];
    const float* conv_b = (const float*)d_in[2];
    const float* wq     = (const float*)d_in[3];
    const float* bq     = (const float*)d_in[4];
    const float* wk     = (const float*)d_in[5];
    const float* bk     = (const float*)d_in[6];
    const float* wv     = (const float*)d_in[7];
    const float* bv     = (const float*)d_in[8];
    const float* wo     = (const float*)d_in[9];
    const float* bo     = (const float*)d_in[10];
    const float* proj_w = (const float*)d_in[11];
    const float* proj_b = (const float*)d_in[12];

    char* ws = (char*)d_ws;
    short* in_pad = (short*)(ws + 0);             // [2][8194][4096]
    short* w_bf   = (short*)(ws + 134283264);     // [3][3072][4096] BT
    short* qkv    = (short*)(ws + 209780736);     // [16384][3072]
    short* wq_t   = (short*)(ws + 310444032);     // [1024][1024] BT
    short* wk_t   = (short*)(ws + 312541184);
    short* wv_t   = (short*)(ws + 314638336);
    short* wo_bf  = (short*)(ws + 316735488);     // [1024][1024]
    short* proj_t = (short*)(ws + 318832640);     // [4096][1024]
    short* WfT    = (short*)(ws + 327221248);     // [4096][1024]
    float* bfused = (float*)(ws + 335609856);     // [4096]
    short* qh_buf = (short*)(ws + 0);             // over in_pad
    short* kh_buf = (short*)(ws + 33554432);
    short* vh_buf = (short*)(ws + 67108864);
    short* o_buf  = (short*)(ws + 134283264);     // over w_bf

    dim3 blk(256), blk5(512);

    pad_convert_inputs<<<16388, blk, 0, stream>>>(inputs, in_pad);
    for (int t = 0; t < 3; ++t)
        transpose_convert<<<dim3(96, 128), blk, 0, stream>>>(
            conv_w + (size_t)t * 4096 * 3072, w_bf + (size_t)t * 3072 * 4096, 4096, 3072);
    transpose_convert<<<dim3(32, 32), blk, 0, stream>>>(wq, wq_t, 1024, 1024);
    transpose_convert<<<dim3(32, 32), blk, 0, stream>>>(wk, wk_t, 1024, 1024);
    transpose_convert<<<dim3(32, 32), blk, 0, stream>>>(wv, wv_t, 1024, 1024);
    transpose_convert<<<dim3(128, 32), blk, 0, stream>>>(proj_w, proj_t, 1024, 4096);
    convert_bf16<<<512, blk, 0, stream>>>(wo, wo_bf, 131072);
    fuse_bias<<<16, blk, 0, stream>>>(bo, proj_w, proj_b, bfused);

    // WfT[dm][he] = sum_w proj_t[dm][w] * wo_flat[he][w]
    gemm256<1, false><<<dim3(4, 16), blk5, 0, stream>>>(
        proj_t, 1024, wo_bf, 1024, 0, WfT, 1024, nullptr, 16);
    // conv as 3-tap GEMM
    gemm256<3, false><<<dim3(12, 64), blk5, 0, stream>>>(
        in_pad, 4096, w_bf, 4096, (long long)3072 * 4096, qkv, 3072, conv_b, 192);
    // head projections
    gemm256<1, false><<<dim3(4, 64), blk5, 0, stream>>>(
        qkv + 0,    3072, wq_t, 1024, 0, qh_buf, 1024, bq, 16);
    gemm256<1, false><<<dim3(4, 64), blk5, 0, stream>>>(
        qkv + 1024, 3072, wk_t, 1024, 0, kh_buf, 1024, bk, 16);
    gemm256<1, false><<<dim3(4, 64), blk5, 0, stream>>>(
        qkv + 2048, 3072, wv_t, 1024, 0, vh_buf, 1024, bv, 16);

    attn_kernel<<<dim3(16, 128), blk, 0, stream>>>(qh_buf, kh_buf, vh_buf, o_buf);

    // out = o @ Wf + bfused   (f32 out)
    gemm256<1, true><<<dim3(16, 64), blk5, 0, stream>>>(
        o_buf, 1024, WfT, 1024, 0, d_out, 4096, bfused, 16);
}

// Round 8
// 1714.600 us; speedup vs baseline: 1.0736x; 1.0736x over previous
//
#include <hip/hip_runtime.h>
#include <hip/hip_bf16.h>
#include <stdint.h>

typedef __attribute__((ext_vector_type(8))) short short8;
typedef __attribute__((ext_vector_type(4))) float f32x4;

#define AS1 __attribute__((address_space(1)))
#define AS3 __attribute__((address_space(3)))

__device__ __forceinline__ short f2bf(float x) {
    __hip_bfloat16 h = __float2bfloat16(x);
    union { __hip_bfloat16 h; short s; } u; u.h = h; return u.s;
}

__device__ __forceinline__ void gload_lds16(const short* g, short* l) {
    __builtin_amdgcn_global_load_lds((const AS1 void*)g, (AS3 void*)l, 16, 0, 0);
}

#define BAR()        asm volatile("s_barrier" ::: "memory")
#define VMCNT_BAR(N) asm volatile("s_waitcnt vmcnt(" #N ")\n\ts_barrier" ::: "memory")

// ---------------------------------------------------------------------------
// 256x256 tile, BK=64 K-tiles, 512 threads = 8 waves (2M x 4N), m201-style
// 4-phase schedule. LDS [2buf][2kh][256][32] x {A,B} = 128 KiB. T2 chunk-XOR
// swizzle (measured 0 conflicts). KEY (r8): each phase's ds_reads are issued
// BEFORE the opening barrier, so barrier wait absorbs LDS latency and MFMA
// starts immediately after (r5 read-after-sync exposed the LDS burst; 46.8%).
// Counted vmcnt ledger (residency confirmed one barrier before first read):
//   t.kh0 <- t-1.ph3 vmcnt(6); t.kh1 <- t.ph1 vmcnt(6).
//   stages: ph0/1 -> (t+1).kh1 (buf^1), ph2/3 -> (t+2).kh0 (buf).
// QKV: block-diagonal merged q/k/v projection -- A col base = n0 & ~1023
// (r7 bug: dense merge read A[:,0:1024] for all three outputs).
// TAPS==3: conv path; A rows remap through padded [2][8194][4096].
// ---------------------------------------------------------------------------
template<int TAPS, bool QKV, bool F32OUT>
__global__ __launch_bounds__(512, 2) void gemm256(
    const short* __restrict__ A, int lda,
    const short* __restrict__ BT, int ldb, long long tapB,
    void* __restrict__ Cout, int ldc,
    const float* __restrict__ bias, int KT)
{
    __shared__ __align__(16) short As[2 * 2 * 256 * 32];
    __shared__ __align__(16) short Bs[2 * 2 * 256 * 32];
    const int tid = threadIdx.x, lane = tid & 63, wid = tid >> 6;
    const int wm = wid >> 2, wn = wid & 3;
    const int m0 = blockIdx.y * 256, n0 = blockIdx.x * 256;
    const size_t arow0 = (TAPS == 3) ? ((size_t)(m0 >> 13) * 8194 + (size_t)(m0 & 8191))
                                     : (size_t)m0;
    const size_t ldaS = (size_t)lda, ldbS = (size_t)ldb, tapBS = (size_t)tapB;
    const short* Abase0 = A + arow0 * ldaS + (QKV ? (n0 & ~1023) : 0);
    const short* Bbase0 = BT + (size_t)n0 * ldbS;
    const int c15 = lane & 15, g4 = (lane >> 4) * 4;
    const int swz = ((lane >> 4) ^ ((c15 >> 1) & 3)) * 8;
    const int srow = tid >> 2;
    const int schunk = (((tid & 3) ^ ((tid >> 3) & 3)) * 8);

#define STG_A(u, kh, buf) do { \
    const int tp_ = (TAPS == 3) ? ((u) >> 6) : 0; \
    const int kc_ = (TAPS == 3) ? (((u) & 63) << 6) : ((u) << 6); \
    const short* g_ = Abase0 + (size_t)tp_ * ldaS + kc_ + (kh) * 32 \
                      + (size_t)srow * ldaS + schunk; \
    short* l_ = As + (buf) * 16384 + (kh) * 8192 + wid * 512; \
    gload_lds16(g_, l_); \
    gload_lds16(g_ + 128 * ldaS, l_ + 4096); \
} while (0)

#define STG_B(u, kh, buf) do { \
    const int tp_ = (TAPS == 3) ? ((u) >> 6) : 0; \
    const int kc_ = (TAPS == 3) ? (((u) & 63) << 6) : ((u) << 6); \
    const short* g_ = Bbase0 + (size_t)tp_ * tapBS + kc_ + (kh) * 32 \
                      + (size_t)srow * ldbS + schunk; \
    short* l_ = Bs + (buf) * 16384 + (kh) * 8192 + wid * 512; \
    gload_lds16(g_, l_); \
    gload_lds16(g_ + 128 * ldbS, l_ + 4096); \
} while (0)

#define LDA_(buf, kk, mi) (*(const short8*)(As + (buf) * 16384 + (kk) * 8192 \
                           + (wm * 128 + (mi) * 16 + c15) * 32 + swz))
#define LDB_(buf, kk, nj) (*(const short8*)(Bs + (buf) * 16384 + (kk) * 8192 \
                           + (wn * 64 + (nj) * 16 + c15) * 32 + swz))

#define MM(mi, nj, Av, Bv) acc[mi][nj] = \
    __builtin_amdgcn_mfma_f32_16x16x32_bf16(Av, Bv, acc[mi][nj], 0, 0, 0)

#define MFMA16(MB) do { \
    __builtin_amdgcn_s_setprio(1); \
    MM((MB)+0, 0, a0, b0); MM((MB)+0, 1, a0, b1); MM((MB)+0, 2, a0, b2); MM((MB)+0, 3, a0, b3); \
    MM((MB)+1, 0, a1, b0); MM((MB)+1, 1, a1, b1); MM((MB)+1, 2, a1, b2); MM((MB)+1, 3, a1, b3); \
    MM((MB)+2, 0, a2, b0); MM((MB)+2, 1, a2, b1); MM((MB)+2, 2, a2, b2); MM((MB)+2, 3, a2, b3); \
    MM((MB)+3, 0, a3, b0); MM((MB)+3, 1, a3, b1); MM((MB)+3, 2, a3, b2); MM((MB)+3, 3, a3, b3); \
    __builtin_amdgcn_s_setprio(0); \
} while (0)

    f32x4 acc[8][4];
    #pragma unroll
    for (int i = 0; i < 8; ++i)
        #pragma unroll
        for (int j = 0; j < 4; ++j)
            acc[i][j] = (f32x4){0.f, 0.f, 0.f, 0.f};

    // prologue: t0.kh0, t0.kh1, t1.kh0 staged (12 loads); confirm t0.kh0
    STG_A(0, 0, 0); STG_B(0, 0, 0); STG_A(0, 1, 0); STG_B(0, 1, 0);
    if (KT > 1) { STG_A(1, 0, 1); STG_B(1, 0, 1); VMCNT_BAR(8); }
    else        { VMCNT_BAR(4); }

    for (int t = 0; t < KT; ++t) {
        const int c = t & 1, nb = c ^ 1;
        const bool st1 = (t + 1 < KT), st2 = (t + 2 < KT);
        short8 a0, a1, a2, a3, b0, b1, b2, b3;

        // ---- ph0: kk0, mi0-3 ----
        a0 = LDA_(c, 0, 0); a1 = LDA_(c, 0, 1); a2 = LDA_(c, 0, 2); a3 = LDA_(c, 0, 3);
        b0 = LDB_(c, 0, 0); b1 = LDB_(c, 0, 1); b2 = LDB_(c, 0, 2); b3 = LDB_(c, 0, 3);
        if (st1) STG_A(t + 1, 1, nb);
        BAR();
        MFMA16(0);
        BAR();

        // ---- ph1: kk0, mi4-7 (b kk0 reused); confirm t.kh1 ----
        a0 = LDA_(c, 0, 4); a1 = LDA_(c, 0, 5); a2 = LDA_(c, 0, 6); a3 = LDA_(c, 0, 7);
        if (st1) STG_B(t + 1, 1, nb);
        if (st1) { VMCNT_BAR(6); } else { VMCNT_BAR(0); }
        MFMA16(4);
        BAR();

        // ---- ph2: kk1, mi0-3 ----
        a0 = LDA_(c, 1, 0); a1 = LDA_(c, 1, 1); a2 = LDA_(c, 1, 2); a3 = LDA_(c, 1, 3);
        b0 = LDB_(c, 1, 0); b1 = LDB_(c, 1, 1); b2 = LDB_(c, 1, 2); b3 = LDB_(c, 1, 3);
        if (st2) STG_A(t + 2, 0, c);
        BAR();
        MFMA16(0);
        BAR();

        // ---- ph3: kk1, mi4-7; confirm (t+1).kh0 ----
        a0 = LDA_(c, 1, 4); a1 = LDA_(c, 1, 5); a2 = LDA_(c, 1, 6); a3 = LDA_(c, 1, 7);
        if (st2) STG_B(t + 2, 0, c);
        if (st2)      { VMCNT_BAR(6); }
        else if (st1) { VMCNT_BAR(4); }
        else          { VMCNT_BAR(0); }
        MFMA16(4);
        BAR();
    }

    float bv[4];
    #pragma unroll
    for (int nj = 0; nj < 4; ++nj)
        bv[nj] = bias ? bias[n0 + wn * 64 + nj * 16 + c15] : 0.f;
    #pragma unroll
    for (int mi = 0; mi < 8; ++mi) {
        #pragma unroll
        for (int r = 0; r < 4; ++r) {
            const size_t row = (size_t)m0 + wm * 128 + mi * 16 + g4 + r;
            #pragma unroll
            for (int nj = 0; nj < 4; ++nj) {
                const int col = n0 + wn * 64 + nj * 16 + c15;
                const float v = acc[mi][nj][r] + bv[nj];
                if (F32OUT) ((float*)Cout)[row * (size_t)ldc + col] = v;
                else        ((short*)Cout)[row * (size_t)ldc + col] = f2bf(v);
            }
        }
    }
#undef STG_A
#undef STG_B
#undef LDA_
#undef LDB_
#undef MM
#undef MFMA16
}

// ---------------------------------------------------------------------------
// Per (head, block) causal attention. qkvh: [16384][3072] bf16, q at cols
// 0-1023, k at +1024, v at +2048 (col within each = h*64+e). obuf [16384][1024].
// ---------------------------------------------------------------------------
__global__ __launch_bounds__(256) void attn_kernel(
    const short* __restrict__ qkvh, short* __restrict__ obuf)
{
    __shared__ __align__(16) char smem[54272];
    short* qs = (short*)smem;                 // [128][72]
    short* ks = (short*)smem + 9216;          // [128][72]
    short* vt = (short*)(smem + 36864);       // [64][136]  (v transposed)
    short* ps = (short*)smem;                 // [128][136] (reuses qs+ks region)
    short* os = (short*)smem;                 // [128][72]  (reused post-PV)

    const int tid = threadIdx.x, lane = tid & 63, wid = tid >> 6;
    const int h = blockIdx.x, b = blockIdx.y;
    const size_t base = (size_t)b * 128 * 3072 + (size_t)h * 64;

    for (int i = tid; i < 1024; i += 256) {
        const int row = i >> 3, c8 = i & 7;
        const size_t g = base + (size_t)row * 3072 + c8 * 8;
        *(short8*)(qs + row * 72 + c8 * 8) = *(const short8*)(qkvh + g);
        *(short8*)(ks + row * 72 + c8 * 8) = *(const short8*)(qkvh + g + 1024);
        short8 vv = *(const short8*)(qkvh + g + 2048);
        #pragma unroll
        for (int j = 0; j < 8; ++j) vt[(c8 * 8 + j) * 136 + row] = vv[j];
    }
    __syncthreads();

    const int c15 = lane & 15, g8 = (lane >> 4) * 8, g4 = (lane >> 4) * 4;
    const int r0 = wid * 32;

    f32x4 sacc[2][8];
    #pragma unroll
    for (int mi = 0; mi < 2; ++mi)
        #pragma unroll
        for (int nj = 0; nj < 8; ++nj)
            sacc[mi][nj] = (f32x4){0.f, 0.f, 0.f, 0.f};
    #pragma unroll
    for (int kk = 0; kk < 2; ++kk) {
        short8 aq[2];
        #pragma unroll
        for (int mi = 0; mi < 2; ++mi)
            aq[mi] = *(const short8*)(qs + (r0 + mi * 16 + c15) * 72 + kk * 32 + g8);
        #pragma unroll
        for (int nj = 0; nj < 8; ++nj) {
            short8 bk8 = *(const short8*)(ks + (nj * 16 + c15) * 72 + kk * 32 + g8);
            #pragma unroll
            for (int mi = 0; mi < 2; ++mi)
                sacc[mi][nj] = __builtin_amdgcn_mfma_f32_16x16x32_bf16(
                    aq[mi], bk8, sacc[mi][nj], 0, 0, 0);
        }
    }
    __syncthreads();

    #pragma unroll
    for (int mi = 0; mi < 2; ++mi) {
        #pragma unroll
        for (int r = 0; r < 4; ++r) {
            const int qrow = r0 + mi * 16 + g4 + r;
            float m = -3.0e38f, pv[8];
            #pragma unroll
            for (int nj = 0; nj < 8; ++nj) {
                float s = sacc[mi][nj][r] * 0.125f;
                if (nj * 16 + c15 > qrow) s = -1.0e9f;
                pv[nj] = s; m = fmaxf(m, s);
            }
            #pragma unroll
            for (int off = 8; off >= 1; off >>= 1) m = fmaxf(m, __shfl_xor(m, off));
            float sum = 0.f;
            #pragma unroll
            for (int nj = 0; nj < 8; ++nj) { float p = __expf(pv[nj] - m); pv[nj] = p; sum += p; }
            #pragma unroll
            for (int off = 8; off >= 1; off >>= 1) sum += __shfl_xor(sum, off);
            const float inv = 1.0f / sum;
            #pragma unroll
            for (int nj = 0; nj < 8; ++nj)
                ps[qrow * 136 + nj * 16 + c15] = f2bf(pv[nj] * inv);
        }
    }
    __syncthreads();

    f32x4 oacc[2][4];
    #pragma unroll
    for (int mi = 0; mi < 2; ++mi)
        #pragma unroll
        for (int nj = 0; nj < 4; ++nj)
            oacc[mi][nj] = (f32x4){0.f, 0.f, 0.f, 0.f};
    #pragma unroll
    for (int kt = 0; kt < 4; ++kt) {
        short8 ap[2];
        #pragma unroll
        for (int mi = 0; mi < 2; ++mi)
            ap[mi] = *(const short8*)(ps + (r0 + mi * 16 + c15) * 136 + kt * 32 + g8);
        #pragma unroll
        for (int nj = 0; nj < 4; ++nj) {
            short8 bv8 = *(const short8*)(vt + (nj * 16 + c15) * 136 + kt * 32 + g8);
            #pragma unroll
            for (int mi = 0; mi < 2; ++mi)
                oacc[mi][nj] = __builtin_amdgcn_mfma_f32_16x16x32_bf16(
                    ap[mi], bv8, oacc[mi][nj], 0, 0, 0);
        }
    }
    __syncthreads();

    #pragma unroll
    for (int mi = 0; mi < 2; ++mi)
        #pragma unroll
        for (int r = 0; r < 4; ++r)
            #pragma unroll
            for (int nj = 0; nj < 4; ++nj)
                os[(r0 + mi * 16 + g4 + r) * 72 + nj * 16 + c15] = f2bf(oacc[mi][nj][r]);
    __syncthreads();

    for (int i = tid; i < 1024; i += 256) {
        const int row = i >> 3, c8 = i & 7;
        *(short8*)(obuf + (size_t)b * 128 * 1024 + (size_t)h * 64
                   + (size_t)row * 1024 + c8 * 8) =
            *(const short8*)(os + row * 72 + c8 * 8);
    }
}

// ---------------------------------------------------------------------------
__global__ void pad_convert_inputs(const float* __restrict__ in, short* __restrict__ out)
{
    const int row = blockIdx.x;                 // [0, 16388)
    const int n = row / 8194, l = row % 8194;
    short* orow = out + (size_t)row * 4096;
    if (l == 0 || l == 8193) {
        for (int i = threadIdx.x; i < 512; i += 256) {
            uint4 z; z.x = z.y = z.z = z.w = 0u;
            *(uint4*)(orow + i * 8) = z;
        }
    } else {
        const float* irow = in + ((size_t)n * 8192 + (l - 1)) * 4096;
        for (int i = threadIdx.x; i < 512; i += 256) {
            float4 a = *(const float4*)(irow + i * 8);
            float4 b = *(const float4*)(irow + i * 8 + 4);
            short8 v;
            v[0] = f2bf(a.x); v[1] = f2bf(a.y); v[2] = f2bf(a.z); v[3] = f2bf(a.w);
            v[4] = f2bf(b.x); v[5] = f2bf(b.y); v[6] = f2bf(b.z); v[7] = f2bf(b.w);
            *(short8*)(orow + i * 8) = v;
        }
    }
}

__global__ void transpose_convert(const float* __restrict__ in, short* __restrict__ out,
                                  int R, int C)
{
    __shared__ float tile[32][33];
    const int tx = threadIdx.x & 31, ty = threadIdx.x >> 5;   // 32 x 8
    const int bx = blockIdx.x * 32, by = blockIdx.y * 32;
    #pragma unroll
    for (int i = 0; i < 32; i += 8)
        tile[ty + i][tx] = in[(size_t)(by + ty + i) * C + bx + tx];
    __syncthreads();
    #pragma unroll
    for (int i = 0; i < 32; i += 8)
        out[(size_t)(bx + ty + i) * R + by + tx] = f2bf(tile[tx][ty + i]);
}

__global__ void convert_bf16(const float* __restrict__ in, short* __restrict__ out, int n8)
{
    const int idx = blockIdx.x * 256 + threadIdx.x;
    if (idx < n8) {
        float4 a = *(const float4*)(in + (size_t)idx * 8);
        float4 b = *(const float4*)(in + (size_t)idx * 8 + 4);
        short8 v;
        v[0] = f2bf(a.x); v[1] = f2bf(a.y); v[2] = f2bf(a.z); v[3] = f2bf(a.w);
        v[4] = f2bf(b.x); v[5] = f2bf(b.y); v[6] = f2bf(b.z); v[7] = f2bf(b.w);
        *(short8*)(out + (size_t)idx * 8) = v;
    }
}

__global__ void fuse_bias(const float* __restrict__ bo, const float* __restrict__ projw,
                          const float* __restrict__ projb, float* __restrict__ outb)
{
    const int j = blockIdx.x * 256 + threadIdx.x;   // 4096
    float s = projb[j];
    for (int w = 0; w < 1024; ++w) s = fmaf(bo[w], projw[(size_t)w * 4096 + j], s);
    outb[j] = s;
}

__global__ void concat_bias(const float* __restrict__ bq, const float* __restrict__ bk,
                            const float* __restrict__ bv, float* __restrict__ outb)
{
    const int j = blockIdx.x * 256 + threadIdx.x;   // 3072
    outb[j] = (j < 1024) ? bq[j] : (j < 2048) ? bk[j - 1024] : bv[j - 2048];
}

// ---------------------------------------------------------------------------
extern "C" void kernel_launch(void* const* d_in, const int* in_sizes, int n_in,
                              void* d_out, int out_size, void* d_ws, size_t ws_size,
                              hipStream_t stream)
{
    const float* inputs = (const float*)d_in[0];
    const float* conv_w = (const float*)d_in[1];
    const float* conv_b = (const float*)d_in[2];
    const float* wq     = (const float*)d_in[3];
    const float* bq     = (const float*)d_in[4];
    const float* wk     = (const float*)d_in[5];
    const float* bk     = (const float*)d_in[6];
    const float* wv     = (const float*)d_in[7];
    const float* bv     = (const float*)d_in[8];
    const float* wo     = (const float*)d_in[9];
    const float* bo     = (const float*)d_in[10];
    const float* proj_w = (const float*)d_in[11];
    const float* proj_b = (const float*)d_in[12];

    char* ws = (char*)d_ws;
    short* in_pad = (short*)(ws + 0);             // [2][8194][4096]
    short* w_bf   = (short*)(ws + 134283264);     // [3][3072][4096] BT
    short* qkv    = (short*)(ws + 209780736);     // [16384][3072] conv out
    short* wq_t   = (short*)(ws + 310444032);     // [3][1024][1024] BT contiguous
    short* wo_bf  = (short*)(ws + 316735488);     // [1024][1024]
    short* proj_t = (short*)(ws + 318832640);     // [4096][1024]
    short* WfT    = (short*)(ws + 327221248);     // [4096][1024]
    float* bfused = (float*)(ws + 335609856);     // [4096]
    float* bqkv   = (float*)(ws + 335626240);     // [3072]
    short* qkvh   = (short*)(ws + 0);             // [16384][3072] over in_pad
    short* o_buf  = (short*)(ws + 134283264);     // [16384][1024] over w_bf

    dim3 blk(256), blk5(512);

    pad_convert_inputs<<<16388, blk, 0, stream>>>(inputs, in_pad);
    for (int t = 0; t < 3; ++t)
        transpose_convert<<<dim3(96, 128), blk, 0, stream>>>(
            conv_w + (size_t)t * 4096 * 3072, w_bf + (size_t)t * 3072 * 4096, 4096, 3072);
    transpose_convert<<<dim3(32, 32), blk, 0, stream>>>(wq, wq_t, 1024, 1024);
    transpose_convert<<<dim3(32, 32), blk, 0, stream>>>(wk, wq_t + 1048576, 1024, 1024);
    transpose_convert<<<dim3(32, 32), blk, 0, stream>>>(wv, wq_t + 2097152, 1024, 1024);
    transpose_convert<<<dim3(128, 32), blk, 0, stream>>>(proj_w, proj_t, 1024, 4096);
    convert_bf16<<<512, blk, 0, stream>>>(wo, wo_bf, 131072);
    fuse_bias<<<16, blk, 0, stream>>>(bo, proj_w, proj_b, bfused);
    concat_bias<<<12, blk, 0, stream>>>(bq, bk, bv, bqkv);

    // WfT[dm][he] = sum_w proj_t[dm][w] * wo_flat[he][w]
    gemm256<1, false, false><<<dim3(4, 16), blk5, 0, stream>>>(
        proj_t, 1024, wo_bf, 1024, 0, WfT, 1024, nullptr, 16);
    // conv as 3-tap GEMM -> qkv [16384][3072]
    gemm256<3, false, false><<<dim3(12, 64), blk5, 0, stream>>>(
        in_pad, 4096, w_bf, 4096, (long long)3072 * 4096, qkv, 3072, conv_b, 192);
    // merged block-diagonal q/k/v head projections -> qkvh [16384][3072]
    gemm256<1, true, false><<<dim3(12, 64), blk5, 0, stream>>>(
        qkv, 3072, wq_t, 1024, 0, qkvh, 3072, bqkv, 16);

    attn_kernel<<<dim3(16, 128), blk, 0, stream>>>(qkvh, o_buf);

    // out = o @ Wf + bfused   (f32 out)
    gemm256<1, false, true><<<dim3(16, 64), blk5, 0, stream>>>(
        o_buf, 1024, WfT, 1024, 0, d_out, 4096, bfused, 16);
}